// Round 2
// baseline (1581.091 us; speedup 1.0000x reference)
//
#include <hip/hip_runtime.h>
#include <hip/hip_bf16.h>
#include <math.h>

// ---------------------------------------------------------------------------
// Threefry-2x32-20 (JAX-compatible), key = (0, 42) from jax.random.key(42).
// Partitionable scheme (JAX >= 0.4.30 default): for flat index j,
//   (b1, b2) = threefry2x32(key, (hi32(j)=0, lo32(j)=j));  bits = b1 ^ b2
// ---------------------------------------------------------------------------
__device__ __forceinline__ unsigned rotl32(unsigned v, int d) {
  return (v << d) | (v >> (32 - d));
}

__device__ __forceinline__ void threefry2x32(unsigned k0, unsigned k1,
                                             unsigned x0, unsigned x1,
                                             unsigned& o0, unsigned& o1) {
  const unsigned ks0 = k0, ks1 = k1, ks2 = k0 ^ k1 ^ 0x1BD11BDAu;
  x0 += ks0; x1 += ks1;
#define RND(r) { x0 += x1; x1 = rotl32(x1, (r)); x1 ^= x0; }
  RND(13) RND(15) RND(26) RND(6)   x0 += ks1; x1 += ks2 + 1u;
  RND(17) RND(29) RND(16) RND(24)  x0 += ks2; x1 += ks0 + 2u;
  RND(13) RND(15) RND(26) RND(6)   x0 += ks0; x1 += ks1 + 3u;
  RND(17) RND(29) RND(16) RND(24)  x0 += ks1; x1 += ks2 + 4u;
  RND(13) RND(15) RND(26) RND(6)   x0 += ks2; x1 += ks0 + 5u;
#undef RND
  o0 = x0; o1 = x1;
}

__device__ __forceinline__ float gumbel_for(unsigned idx) {
  unsigned o0, o1;
  threefry2x32(0u, 42u, 0u, idx, o0, o1);
  const unsigned bits = o0 ^ o1;  // partitionable 32-bit fold
  const float f = __uint_as_float((bits >> 9) | 0x3f800000u) - 1.0f;  // [0,1)
  const float u = fmaxf(f, 1.1754944e-38f);  // jax: max(minval=tiny, f)
  return -logf(-logf(u));
}

// ---------------------------------------------------------------------------
// Kernel A: h_read[m,k] = sum_s h[m,s] * w_read[s,k]   (M=4096, K=512, 16 out)
// ---------------------------------------------------------------------------
__global__ __launch_bounds__(256)
void hread_kernel(const float* __restrict__ h, const float* __restrict__ w_read,
                  float* __restrict__ h_read) {
  __shared__ float Ws[512][17];  // +1 pad col: conflict-free strided reads
  const int tid = threadIdx.x;
  for (int i = tid; i < 512 * 16; i += 256) Ws[i >> 4][i & 15] = w_read[i];
  __syncthreads();
  const int wave = tid >> 6, lane = tid & 63;
  const int m = blockIdx.x * 4 + wave;
  float acc[16];
#pragma unroll
  for (int k = 0; k < 16; ++k) acc[k] = 0.f;
  const float* hrow = h + m * 512;
#pragma unroll
  for (int i = 0; i < 8; ++i) {
    const int s = i * 64 + lane;
    const float hv = hrow[s];
#pragma unroll
    for (int k = 0; k < 16; ++k) acc[k] = fmaf(hv, Ws[s][k], acc[k]);
  }
#pragma unroll
  for (int off = 32; off >= 1; off >>= 1) {
#pragma unroll
    for (int k = 0; k < 16; ++k) acc[k] += __shfl_down(acc[k], off, 64);
  }
  if (lane == 0) {
#pragma unroll
    for (int k = 0; k < 16; ++k) h_read[m * 16 + k] = acc[k];
  }
}

// ---------------------------------------------------------------------------
// Kernel B: fused grouped GEMM + GRU gates -> hnext[m, t, s]
// Block: (m-tile 64) x (template t) x (s-tile 64); computes 6 acc tiles
// (r,z,n for x-side and h-side), K=512 each, then applies gates.
// ---------------------------------------------------------------------------
#define BM 64
#define BS 64
#define KB 32

__global__ __launch_bounds__(256, 2)
void gru_kernel(const float* __restrict__ x, const float* __restrict__ h,
                const float* __restrict__ W_ih, const float* __restrict__ W_hh,
                const float* __restrict__ b_ih, const float* __restrict__ b_hh,
                float* __restrict__ hnext) {
  __shared__ float As[KB][BM];        // 8 KB  (transposed: As[k][m])
  __shared__ float Bs[KB][3 * BS];    // 24 KB (Bs[k][gate*64 + s])

  const int tid = threadIdx.x;
  const int m0 = blockIdx.x * BM;
  const int t  = blockIdx.y;
  const int s0 = blockIdx.z * BS;
  const int mt = tid >> 4;   // 0..15 -> 4 m rows each
  const int nt = tid & 15;   // 0..15 -> 4 s cols each (per gate)

  float accX[3][4][4], accH[3][4][4];
#pragma unroll
  for (int g = 0; g < 3; ++g)
#pragma unroll
    for (int a = 0; a < 4; ++a)
#pragma unroll
      for (int b = 0; b < 4; ++b) { accX[g][a][b] = 0.f; accH[g][a][b] = 0.f; }

  auto run_phase = [&](const float* __restrict__ A, const float* __restrict__ W,
                       float (&acc)[3][4][4]) {
    for (int k0 = 0; k0 < 512; k0 += KB) {
      __syncthreads();
      // stage A: 64 rows x 32 k  (512 float4, 2/thread), transposed store
#pragma unroll
      for (int i = 0; i < 2; ++i) {
        const int idx = i * 256 + tid;
        const int r = idx >> 3, kc = (idx & 7) * 4;
        const float4 v = *(const float4*)&A[(m0 + r) * 512 + k0 + kc];
        As[kc + 0][r] = v.x; As[kc + 1][r] = v.y;
        As[kc + 2][r] = v.z; As[kc + 3][r] = v.w;
      }
      // stage B: 192 weight rows (3 gates x 64 s) x 32 k (1536 float4, 6/thread)
#pragma unroll
      for (int i = 0; i < 6; ++i) {
        const int idx = i * 256 + tid;
        const int row = idx >> 3, kc = (idx & 7) * 4;
        const int g = row >> 6, sl = row & 63;
        const float4 v =
            *(const float4*)&W[((size_t)t * 1536 + g * 512 + s0 + sl) * 512 + k0 + kc];
        Bs[kc + 0][row] = v.x; Bs[kc + 1][row] = v.y;
        Bs[kc + 2][row] = v.z; Bs[kc + 3][row] = v.w;
      }
      __syncthreads();
#pragma unroll
      for (int kk = 0; kk < KB; ++kk) {
        const float4 a4 = *(const float4*)&As[kk][mt * 4];
        const float4 b0 = *(const float4*)&Bs[kk][0 * BS + nt * 4];
        const float4 b1 = *(const float4*)&Bs[kk][1 * BS + nt * 4];
        const float4 b2 = *(const float4*)&Bs[kk][2 * BS + nt * 4];
        const float am[4] = {a4.x, a4.y, a4.z, a4.w};
        const float bb[3][4] = {{b0.x, b0.y, b0.z, b0.w},
                                {b1.x, b1.y, b1.z, b1.w},
                                {b2.x, b2.y, b2.z, b2.w}};
#pragma unroll
        for (int g = 0; g < 3; ++g)
#pragma unroll
          for (int a = 0; a < 4; ++a)
#pragma unroll
            for (int b = 0; b < 4; ++b)
              acc[g][a][b] = fmaf(am[a], bb[g][b], acc[g][a][b]);
      }
    }
  };
  run_phase(x, W_ih, accX);
  run_phase(h, W_hh, accH);

  // epilogue: gates + hnext store
  const float* bi = b_ih + t * 1536;
  const float* bh = b_hh + t * 1536;
#pragma unroll
  for (int a = 0; a < 4; ++a) {
    const int m = m0 + mt * 4 + a;
    const int sg0 = s0 + nt * 4;
    const float4 hv = *(const float4*)&h[m * 512 + sg0];
    const float hm[4] = {hv.x, hv.y, hv.z, hv.w};
    float o[4];
#pragma unroll
    for (int b = 0; b < 4; ++b) {
      const int sg = sg0 + b;
      const float rx = accX[0][a][b] + bi[sg];
      const float rh = accH[0][a][b] + bh[sg];
      const float zx = accX[1][a][b] + bi[512 + sg];
      const float zh = accH[1][a][b] + bh[512 + sg];
      const float nx = accX[2][a][b] + bi[1024 + sg];
      const float nh = accH[2][a][b] + bh[1024 + sg];
      const float r = 1.0f / (1.0f + expf(-(rx + rh)));
      const float z = 1.0f / (1.0f + expf(-(zx + zh)));
      const float n = tanhf(fmaf(r, nh, nx));
      o[b] = (1.0f - z) * n + z * hm[b];
    }
    float4 outv; outv.x = o[0]; outv.y = o[1]; outv.z = o[2]; outv.w = o[3];
    *(float4*)&hnext[(((size_t)m * 8) + t) * 512 + sg0] = outv;
  }
}

// ---------------------------------------------------------------------------
// Kernel C1: logits[m,t] = h_read[m,:] . (hnext[m,t,:] @ w_write[t])
// Block: 64 m-rows x one t; 4 threads/row split K=512.
// ---------------------------------------------------------------------------
__global__ __launch_bounds__(256)
void logits_kernel(const float* __restrict__ hnext, const float* __restrict__ w_write,
                   const float* __restrict__ h_read, float* __restrict__ logits) {
  __shared__ float Ws[512 * 16];    // 32 KB, w_write[t] flat
  __shared__ float red[64][4][16];  // 16 KB
  const int tid = threadIdx.x;
  const int t = blockIdx.y;
  const int m0 = blockIdx.x * 64;
  for (int i = tid; i < 512 * 16; i += 256) Ws[i] = w_write[t * 8192 + i];
  __syncthreads();
  const int mi = tid >> 2, q = tid & 3;
  const int m = m0 + mi;
  float4 wk[4];
#pragma unroll
  for (int k4 = 0; k4 < 4; ++k4) wk[k4] = make_float4(0.f, 0.f, 0.f, 0.f);
  const float4* hv4 = (const float4*)&hnext[(((size_t)m * 8) + t) * 512 + q * 128];
  for (int i = 0; i < 32; ++i) {
    const float4 v = hv4[i];
    const float vv[4] = {v.x, v.y, v.z, v.w};
#pragma unroll
    for (int j = 0; j < 4; ++j) {
      const int s = q * 128 + i * 4 + j;
#pragma unroll
      for (int k4 = 0; k4 < 4; ++k4) {
        const float4 w = *(const float4*)&Ws[s * 16 + k4 * 4];  // broadcast read
        wk[k4].x = fmaf(vv[j], w.x, wk[k4].x);
        wk[k4].y = fmaf(vv[j], w.y, wk[k4].y);
        wk[k4].z = fmaf(vv[j], w.z, wk[k4].z);
        wk[k4].w = fmaf(vv[j], w.w, wk[k4].w);
      }
    }
  }
#pragma unroll
  for (int k4 = 0; k4 < 4; ++k4) {
    red[mi][q][k4 * 4 + 0] = wk[k4].x; red[mi][q][k4 * 4 + 1] = wk[k4].y;
    red[mi][q][k4 * 4 + 2] = wk[k4].z; red[mi][q][k4 * 4 + 3] = wk[k4].w;
  }
  __syncthreads();
  if (q == 0) {
    float lg = 0.f;
#pragma unroll
    for (int k = 0; k < 16; ++k) {
      const float w = red[mi][0][k] + red[mi][1][k] + red[mi][2][k] + red[mi][3][k];
      lg = fmaf(h_read[m * 16 + k], w, lg);
    }
    logits[m * 8 + t] = lg;
  }
}

// ---------------------------------------------------------------------------
// Kernel C2: gumbel + argmax (first-wins, matching jnp.argmax), att one-hot,
// hout[m,:] = hnext[m, t*, :].  One wave per m-row.
// ---------------------------------------------------------------------------
__global__ __launch_bounds__(256)
void select_kernel(const float* __restrict__ logits, const float* __restrict__ hnext,
                   float* __restrict__ out) {
  const int tid = threadIdx.x;
  const int wave = tid >> 6, lane = tid & 63;
  const int m = blockIdx.x * 4 + wave;
  int bt = 0;
  if (lane == 0) {
    float best = -3.4e38f;
#pragma unroll
    for (int t = 0; t < 8; ++t) {
      const float g = gumbel_for((unsigned)(m * 8 + t));
      const float pv = (logits[m * 8 + t] + g) * 2.0f;  // /tau, tau=0.5 (exact)
      if (pv > best) { best = pv; bt = t; }              // strict >: first-wins
    }
  }
  bt = __shfl(bt, 0, 64);
  if (lane < 8) out[2097152 + m * 8 + lane] = (lane == bt) ? 1.0f : 0.0f;
  const float4* src = (const float4*)hnext + (((size_t)m * 8) + bt) * 128;
  float4* dst = (float4*)out + (size_t)m * 128;
  dst[lane] = src[lane];
  dst[lane + 64] = src[lane + 64];
}

// ---------------------------------------------------------------------------
extern "C" void kernel_launch(void* const* d_in, const int* in_sizes, int n_in,
                              void* d_out, int out_size, void* d_ws, size_t ws_size,
                              hipStream_t stream) {
  const float* x       = (const float*)d_in[0];  // input  [512,4096] -> [4096,512]
  const float* h       = (const float*)d_in[1];  // h      [512,4096] -> [4096,512]
  const float* W_ih    = (const float*)d_in[2];  // [8,1536,512]
  const float* W_hh    = (const float*)d_in[3];  // [8,1536,512]
  const float* b_ih    = (const float*)d_in[4];  // [8,1536]
  const float* b_hh    = (const float*)d_in[5];  // [8,1536]
  const float* w_read  = (const float*)d_in[6];  // [1,512,16]
  const float* w_write = (const float*)d_in[7];  // [8,512,16]
  float* out = (float*)d_out;                    // hout [512*4096] ++ att [512*64]

  float* hnext  = (float*)d_ws;                       // 16,777,216 f32 (64 MB)
  float* h_read = hnext + (size_t)4096 * 8 * 512;     //     65,536 f32
  float* logits = h_read + (size_t)4096 * 16;         //     32,768 f32

  hread_kernel<<<dim3(1024), dim3(256), 0, stream>>>(h, w_read, h_read);
  gru_kernel<<<dim3(64, 8, 8), dim3(256), 0, stream>>>(x, h, W_ih, W_hh, b_ih, b_hh, hnext);
  logits_kernel<<<dim3(64, 8), dim3(256), 0, stream>>>(hnext, w_write, h_read, logits);
  select_kernel<<<dim3(1024), dim3(256), 0, stream>>>(logits, hnext, out);
}

// Round 4
// 510.422 us; speedup vs baseline: 3.0976x; 3.0976x over previous
//
#include <hip/hip_runtime.h>
#include <hip/hip_bf16.h>
#include <math.h>

typedef __attribute__((ext_vector_type(8))) short short8;
typedef __attribute__((ext_vector_type(16))) float f32x16;

__device__ __forceinline__ short8 as_s8(uint4 v) {
  union { uint4 u; short8 s; } x; x.u = v; return x.s;
}
__device__ __forceinline__ unsigned cvt_pk_bf16(float a, float b) {
  unsigned r;
  asm volatile("v_cvt_pk_bf16_f32 %0, %1, %2" : "=v"(r) : "v"(a), "v"(b));
  return r;  // lo16 = bf16(a), hi16 = bf16(b)
}

// ---------------------------------------------------------------------------
// Threefry-2x32-20 (JAX), key=(0,42); partitionable fold (verified R2: passed)
// ---------------------------------------------------------------------------
__device__ __forceinline__ unsigned rotl32(unsigned v, int d) {
  return (v << d) | (v >> (32 - d));
}
__device__ __forceinline__ void threefry2x32(unsigned k0, unsigned k1,
                                             unsigned x0, unsigned x1,
                                             unsigned& o0, unsigned& o1) {
  const unsigned ks0 = k0, ks1 = k1, ks2 = k0 ^ k1 ^ 0x1BD11BDAu;
  x0 += ks0; x1 += ks1;
#define RND(r) { x0 += x1; x1 = rotl32(x1, (r)); x1 ^= x0; }
  RND(13) RND(15) RND(26) RND(6)   x0 += ks1; x1 += ks2 + 1u;
  RND(17) RND(29) RND(16) RND(24)  x0 += ks2; x1 += ks0 + 2u;
  RND(13) RND(15) RND(26) RND(6)   x0 += ks0; x1 += ks1 + 3u;
  RND(17) RND(29) RND(16) RND(24)  x0 += ks1; x1 += ks2 + 4u;
  RND(13) RND(15) RND(26) RND(6)   x0 += ks2; x1 += ks0 + 5u;
#undef RND
  o0 = x0; o1 = x1;
}
__device__ __forceinline__ float gumbel_for(unsigned idx) {
  unsigned o0, o1;
  threefry2x32(0u, 42u, 0u, idx, o0, o1);
  const unsigned bits = o0 ^ o1;
  const float f = __uint_as_float((bits >> 9) | 0x3f800000u) - 1.0f;
  const float u = fmaxf(f, 1.1754944e-38f);
  return -logf(-logf(u));
}

// ---------------------------------------------------------------------------
// Kernel A: h_read[m,k] = sum_s h[m,s]*w_read[s,k]  (f32-exact for logits path)
// ---------------------------------------------------------------------------
__global__ __launch_bounds__(256)
void hread_kernel(const float* __restrict__ h, const float* __restrict__ w_read,
                  float* __restrict__ h_read) {
  __shared__ float Ws[512][17];
  const int tid = threadIdx.x;
  for (int i = tid; i < 512 * 16; i += 256) Ws[i >> 4][i & 15] = w_read[i];
  __syncthreads();
  const int wave = tid >> 6, lane = tid & 63;
  const int m = blockIdx.x * 4 + wave;
  float acc[16];
#pragma unroll
  for (int k = 0; k < 16; ++k) acc[k] = 0.f;
  const float* hrow = h + (size_t)m * 512;
#pragma unroll
  for (int i = 0; i < 8; ++i) {
    const int s = i * 64 + lane;
    const float hv = hrow[s];
#pragma unroll
    for (int k = 0; k < 16; ++k) acc[k] = fmaf(hv, Ws[s][k], acc[k]);
  }
#pragma unroll
  for (int off = 32; off >= 1; off >>= 1) {
#pragma unroll
    for (int k = 0; k < 16; ++k) acc[k] += __shfl_down(acc[k], off, 64);
  }
  if (lane == 0) {
#pragma unroll
    for (int k = 0; k < 16; ++k) h_read[m * 16 + k] = acc[k];
  }
}

// ---------------------------------------------------------------------------
// Kernel B: MFMA GRU. Block = 256m x 64s x one t. 512 thr = 8 waves (4x2),
// wave-tile 64m x 32s of v_mfma_f32_32x32x16_bf16. Split-bf16 3-pass
// (hi*hi + hi*lo + lo*hi). K-concat for r,z gates (x-side + h-side share acc).
// LDS rows = 128 B: [hi: 4x16B chunks | lo: 4x16B], chunk index XOR (row&7).
// ---------------------------------------------------------------------------
__device__ __forceinline__ void stage8(const float* __restrict__ src,
                                       unsigned char* ldsrow, int grp, int row) {
  const float4 v0 = *(const float4*)src;
  const float4 v1 = *(const float4*)(src + 4);
  const unsigned h0 = cvt_pk_bf16(v0.x, v0.y);
  const unsigned h1 = cvt_pk_bf16(v0.z, v0.w);
  const unsigned h2 = cvt_pk_bf16(v1.x, v1.y);
  const unsigned h3 = cvt_pk_bf16(v1.z, v1.w);
  const float l0 = v0.x - __uint_as_float(h0 << 16);
  const float l1 = v0.y - __uint_as_float(h0 & 0xFFFF0000u);
  const float l2 = v0.z - __uint_as_float(h1 << 16);
  const float l3 = v0.w - __uint_as_float(h1 & 0xFFFF0000u);
  const float l4 = v1.x - __uint_as_float(h2 << 16);
  const float l5 = v1.y - __uint_as_float(h2 & 0xFFFF0000u);
  const float l6 = v1.z - __uint_as_float(h3 << 16);
  const float l7 = v1.w - __uint_as_float(h3 & 0xFFFF0000u);
  const unsigned q0 = cvt_pk_bf16(l0, l1);
  const unsigned q1 = cvt_pk_bf16(l2, l3);
  const unsigned q2 = cvt_pk_bf16(l4, l5);
  const unsigned q3 = cvt_pk_bf16(l6, l7);
  uint4 hi; hi.x = h0; hi.y = h1; hi.z = h2; hi.w = h3;
  uint4 lo; lo.x = q0; lo.y = q1; lo.z = q2; lo.w = q3;
  *(uint4*)(ldsrow + (((grp) ^ (row & 7)) << 4)) = hi;
  *(uint4*)(ldsrow + (((grp + 4) ^ (row & 7)) << 4)) = lo;
}

__device__ __forceinline__ short8 fragld(const unsigned char* base, int row, int c) {
  return as_s8(*(const uint4*)(base + row * 128 + (((c) ^ (row & 7)) << 4)));
}

#define MFMA32(a, b, c) __builtin_amdgcn_mfma_f32_32x32x16_bf16((a), (b), (c), 0, 0, 0)

__global__ __launch_bounds__(512, 2)
void gru_mfma(const float* __restrict__ x, const float* __restrict__ h,
              const float* __restrict__ W_ih, const float* __restrict__ W_hh,
              const float* __restrict__ b_ih, const float* __restrict__ b_hh,
              float* __restrict__ hnext) {
  // LDS: XH region rows 0..511 (x:0-255, h:256-511) @0, W region rows 0..383
  // (W_ih gates r,z,n = rows 0..191; W_hh = rows 192..383) @65536. 112 KB.
  __shared__ __align__(16) unsigned char lds[114688];
  unsigned char* ldsW = lds + 65536;

  const int tid = threadIdx.x;
  const int m0 = blockIdx.x * 256;
  const int t  = blockIdx.y;
  const int s0 = blockIdx.z * 64;
  const int lane = tid & 63;
  const int wid  = tid >> 6;
  const int wm   = wid >> 1;   // 0..3 -> 64 m each
  const int wsc  = wid & 1;    // 0..1 -> 32 s each

  f32x16 acc_r[2], acc_z[2], acc_nx[2], acc_nh[2];
#pragma unroll
  for (int mf = 0; mf < 2; ++mf) {
#pragma unroll
    for (int j = 0; j < 16; ++j) {
      acc_r[mf][j] = 0.f; acc_z[mf][j] = 0.f; acc_nx[mf][j] = 0.f; acc_nh[mf][j] = 0.f;
    }
  }

  for (int k0 = 0; k0 < 512; k0 += 32) {
    // ---- stage: 3584 row-groups of 8 f32 (XH: 2048, W: 1536) = 7/thread ----
#pragma unroll
    for (int i = 0; i < 7; ++i) {
      const int tau = i * 512 + tid;
      if (tau < 2048) {
        const int row = tau >> 2, grp = tau & 3;
        const float* p = (row < 256) ? (x + (size_t)(m0 + row) * 512)
                                     : (h + (size_t)(m0 + row - 256) * 512);
        stage8(p + k0 + grp * 8, lds + row * 128, grp, row);
      } else {
        const int tw = tau - 2048;
        const int row = tw >> 2, grp = tw & 3;
        const float* p;
        if (row < 192)
          p = W_ih + ((size_t)t * 1536 + (row >> 6) * 512 + s0 + (row & 63)) * 512;
        else
          p = W_hh + ((size_t)t * 1536 + ((row - 192) >> 6) * 512 + s0 + ((row - 192) & 63)) * 512;
        stage8(p + k0 + grp * 8, ldsW + row * 128, grp, row);
      }
    }
    __syncthreads();

    // ---- compute: 2 K-chunks x 3 gates x 2 m-frags x (3-pass x 2 sides) ----
#pragma unroll
    for (int ch = 0; ch < 2; ++ch) {
      const int c = ch * 2 + (lane >> 5);  // hi chunk index 0..3
      short8 xa_h[2], xa_l[2], ha_h[2], ha_l[2];
#pragma unroll
      for (int mf = 0; mf < 2; ++mf) {
        const int rx = wm * 64 + mf * 32 + (lane & 31);
        xa_h[mf] = fragld(lds, rx, c);
        xa_l[mf] = fragld(lds, rx, c + 4);
        ha_h[mf] = fragld(lds, 256 + rx, c);
        ha_l[mf] = fragld(lds, 256 + rx, c + 4);
      }
#pragma unroll
      for (int g = 0; g < 3; ++g) {
        const int wr = g * 64 + wsc * 32 + (lane & 31);
        const short8 bih_h = fragld(ldsW, wr, c);
        const short8 bih_l = fragld(ldsW, wr, c + 4);
        const short8 bhh_h = fragld(ldsW, 192 + wr, c);
        const short8 bhh_l = fragld(ldsW, 192 + wr, c + 4);
#pragma unroll
        for (int mf = 0; mf < 2; ++mf) {
          if (g == 0) {
            acc_r[mf] = MFMA32(xa_h[mf], bih_h, acc_r[mf]);
            acc_r[mf] = MFMA32(xa_h[mf], bih_l, acc_r[mf]);
            acc_r[mf] = MFMA32(xa_l[mf], bih_h, acc_r[mf]);
            acc_r[mf] = MFMA32(ha_h[mf], bhh_h, acc_r[mf]);
            acc_r[mf] = MFMA32(ha_h[mf], bhh_l, acc_r[mf]);
            acc_r[mf] = MFMA32(ha_l[mf], bhh_h, acc_r[mf]);
          } else if (g == 1) {
            acc_z[mf] = MFMA32(xa_h[mf], bih_h, acc_z[mf]);
            acc_z[mf] = MFMA32(xa_h[mf], bih_l, acc_z[mf]);
            acc_z[mf] = MFMA32(xa_l[mf], bih_h, acc_z[mf]);
            acc_z[mf] = MFMA32(ha_h[mf], bhh_h, acc_z[mf]);
            acc_z[mf] = MFMA32(ha_h[mf], bhh_l, acc_z[mf]);
            acc_z[mf] = MFMA32(ha_l[mf], bhh_h, acc_z[mf]);
          } else {
            acc_nx[mf] = MFMA32(xa_h[mf], bih_h, acc_nx[mf]);
            acc_nx[mf] = MFMA32(xa_h[mf], bih_l, acc_nx[mf]);
            acc_nx[mf] = MFMA32(xa_l[mf], bih_h, acc_nx[mf]);
            acc_nh[mf] = MFMA32(ha_h[mf], bhh_h, acc_nh[mf]);
            acc_nh[mf] = MFMA32(ha_h[mf], bhh_l, acc_nh[mf]);
            acc_nh[mf] = MFMA32(ha_l[mf], bhh_h, acc_nh[mf]);
          }
        }
      }
    }
    __syncthreads();
  }

  // ---- epilogue: gates + coalesced f32 hnext store ----
  const int sg = s0 + wsc * 32 + (lane & 31);
  const float bir = b_ih[t * 1536 + sg],        bhr = b_hh[t * 1536 + sg];
  const float biz = b_ih[t * 1536 + 512 + sg],  bhz = b_hh[t * 1536 + 512 + sg];
  const float bin = b_ih[t * 1536 + 1024 + sg], bhn = b_hh[t * 1536 + 1024 + sg];
#pragma unroll
  for (int mf = 0; mf < 2; ++mf) {
#pragma unroll
    for (int r = 0; r < 16; ++r) {
      const int m = m0 + wm * 64 + mf * 32 + ((r & 3) + 8 * (r >> 2) + 4 * (lane >> 5));
      const float rs = acc_r[mf][r] + bir + bhr;
      const float zs = acc_z[mf][r] + biz + bhz;
      const float rg = 1.0f / (1.0f + expf(-rs));
      const float zg = 1.0f / (1.0f + expf(-zs));
      const float n  = tanhf(acc_nx[mf][r] + bin + rg * (acc_nh[mf][r] + bhn));
      const float hm = h[(size_t)m * 512 + sg];
      hnext[((size_t)m * 8 + t) * 512 + sg] = (1.0f - zg) * n + zg * hm;
    }
  }
}

// ---------------------------------------------------------------------------
// Kernel C1: wk[m,t,k] = sum_s hnext[m,t,s]*w_write[t,s,k]  (f32, full s/block)
// ---------------------------------------------------------------------------
__global__ __launch_bounds__(256)
void wkey_kernel(const float* __restrict__ hnext, const float* __restrict__ w_write,
                 float* __restrict__ wk) {
  __shared__ float tile[64][132];   // +pad: mi*132 mod 32 spreads banks
  __shared__ float wlds[128][16];
  const int tid = threadIdx.x;
  const int m0 = blockIdx.x * 64, t = blockIdx.y;
  const int mi = tid >> 2, kq = tid & 3;
  float a0 = 0.f, a1 = 0.f, a2 = 0.f, a3 = 0.f;
  for (int sb = 0; sb < 4; ++sb) {
    __syncthreads();
#pragma unroll
    for (int i = 0; i < 8; ++i) {
      const int tau = i * 256 + tid;
      const int r = tau >> 5, c = (tau & 31) * 4;
      *(float4*)&tile[r][c] =
          *(const float4*)&hnext[((size_t)(m0 + r) * 8 + t) * 512 + sb * 128 + c];
    }
#pragma unroll
    for (int i = 0; i < 2; ++i) {
      const int tau = i * 256 + tid;
      const int r = tau >> 2, c = (tau & 3) * 4;
      *(float4*)&wlds[r][c] =
          *(const float4*)&w_write[(size_t)t * 8192 + (sb * 128 + r) * 16 + c];
    }
    __syncthreads();
    for (int s = 0; s < 128; ++s) {
      const float v = tile[mi][s];
      const float4 w = *(const float4*)&wlds[s][kq * 4];
      a0 = fmaf(v, w.x, a0); a1 = fmaf(v, w.y, a1);
      a2 = fmaf(v, w.z, a2); a3 = fmaf(v, w.w, a3);
    }
  }
  float4 o; o.x = a0; o.y = a1; o.z = a2; o.w = a3;
  *(float4*)&wk[(size_t)(m0 + mi) * 128 + t * 16 + kq * 4] = o;
}

// ---------------------------------------------------------------------------
// Kernel C2: logits + gumbel + argmax (first-wins) + att one-hot + hout gather
// One wave per m-row.
// ---------------------------------------------------------------------------
__global__ __launch_bounds__(256)
void select_kernel(const float* __restrict__ h_read, const float* __restrict__ wk,
                   const float* __restrict__ hnext, float* __restrict__ out) {
  const int tid = threadIdx.x;
  const int wave = tid >> 6, lane = tid & 63;
  const int m = blockIdx.x * 4 + wave;
  float y = -3.4e38f;
  int bt = lane & 7;
  if (lane < 8) {
    float lg = 0.f;
#pragma unroll
    for (int k = 0; k < 16; ++k)
      lg = fmaf(h_read[m * 16 + k], wk[(size_t)m * 128 + lane * 16 + k], lg);
    y = (lg + gumbel_for((unsigned)(m * 8 + lane))) * 2.0f;  // /tau, tau=0.5
  }
#pragma unroll
  for (int off = 4; off >= 1; off >>= 1) {
    const float y2 = __shfl_xor(y, off, 8);
    const int b2 = __shfl_xor(bt, off, 8);
    if (y2 > y || (y2 == y && b2 < bt)) { y = y2; bt = b2; }
  }
  bt = __shfl(bt, 0, 64);
  if (lane < 8) out[2097152 + m * 8 + lane] = (lane == bt) ? 1.0f : 0.0f;
  const float4* src = (const float4*)hnext + ((size_t)m * 8 + bt) * 128;
  float4* dst = (float4*)out + (size_t)m * 128;
  dst[lane] = src[lane];
  dst[lane + 64] = src[lane + 64];
}

// ---------------------------------------------------------------------------
extern "C" void kernel_launch(void* const* d_in, const int* in_sizes, int n_in,
                              void* d_out, int out_size, void* d_ws, size_t ws_size,
                              hipStream_t stream) {
  const float* x       = (const float*)d_in[0];
  const float* h       = (const float*)d_in[1];
  const float* W_ih    = (const float*)d_in[2];
  const float* W_hh    = (const float*)d_in[3];
  const float* b_ih    = (const float*)d_in[4];
  const float* b_hh    = (const float*)d_in[5];
  const float* w_read  = (const float*)d_in[6];
  const float* w_write = (const float*)d_in[7];
  float* out = (float*)d_out;

  float* hnext  = (float*)d_ws;                       // 16,777,216 f32 (64 MB)
  float* wk     = hnext + (size_t)4096 * 8 * 512;     //    524,288 f32 (2 MB)
  float* h_read = wk + (size_t)4096 * 128;            //     65,536 f32
  // total ws use: 66.25 MB (<= known-good 67.6 MB)

  hread_kernel<<<dim3(1024), dim3(256), 0, stream>>>(h, w_read, h_read);
  gru_mfma<<<dim3(16, 8, 8), dim3(512), 0, stream>>>(x, h, W_ih, W_hh, b_ih, b_hh, hnext);
  wkey_kernel<<<dim3(64, 8), dim3(256), 0, stream>>>(hnext, w_write, wk);
  select_kernel<<<dim3(1024), dim3(256), 0, stream>>>(h_read, wk, hnext, out);
}